// Round 1
// baseline (68.259 us; speedup 1.0000x reference)
//
#include <hip/hip_runtime.h>
#include <hip/hip_cooperative_groups.h>
#include <stdint.h>

#define ETA    3.0f
#define KCAP   96
#define POS_W  1.2f
#define NG     64
#define BATCH  4
#define HH     192
#define WW     192
#define NCELL  (HH*WW)
#define NCLS   4
#define CAP    4096
#define PTHR   256
#define NWAVE  4
#define NBLK   (BATCH*NG)          /* 256 pair blocks == whole grid */
#define INF64  0xFFFFFFFFFFFFFFFFull
#define FIXS   67108864.0f         /* 2^26 fixed-point scale (per-term rn) */
#define INV_FIXS (1.0 / 67108864.0)

/* ws layout (ALL state initialized in-kernel; no memset dispatch):
   [0]          cellkey u64[B*NCELL]   (phase-0 init to INF64)
   [WS_PA_OFF]  pA float4[NBLK]        (per-pair float partials)
   [WS_PB_OFF]  pB int64[NBLK]         (per-pair fixed-point picked partials) */
#define WS_PA_OFF (BATCH*NCELL*8)      /* 1179648, 16-aligned */
#define WS_PB_OFF (WS_PA_OFF + NBLK*16)

#define OBJ4_PER_BLK 144   /* (B*NCELL floats / 4) / NBLK */

namespace cg = cooperative_groups;

__device__ __forceinline__ float log_sigmoid(float x) {
    return fminf(x, 0.0f) - __logf(1.0f + __expf(-fabsf(x)));
}

__device__ __forceinline__ float segsq(float wx, float wy, float vx, float vy, float inv) {
    float t = (wx * vx + wy * vy) * inv;
    t = fminf(fmaxf(t, 0.0f), 1.0f);
    float dx = wx - t * vx;
    float dy = wy - t * vy;
    return dx * dx + dy * dy;
}

/* reduce 3 floats + 1 int64 across the block; results valid on tid 0.
   Fixed tree order -> deterministic given the same per-thread partials. */
__device__ __forceinline__ void block_red(float a, float b, float c, long long f,
                                          float* s3, long long* s1,
                                          float out3[3], long long* outf) {
    #pragma unroll
    for (int off = 32; off > 0; off >>= 1) {
        a += __shfl_down(a, off);
        b += __shfl_down(b, off);
        c += __shfl_down(c, off);
        f += __shfl_down(f, off);
    }
    const int lane = threadIdx.x & 63;
    const int wid  = threadIdx.x >> 6;
    __syncthreads();
    if (lane == 0) { s3[wid*3+0]=a; s3[wid*3+1]=b; s3[wid*3+2]=c; s1[wid]=f; }
    __syncthreads();
    if (threadIdx.x == 0) {
        float ra=0.0f, rb=0.0f, rc=0.0f; long long rf=0;
        #pragma unroll
        for (int w = 0; w < NWAVE; ++w) {
            ra += s3[w*3+0]; rb += s3[w*3+1]; rc += s3[w*3+2]; rf += s1[w];
        }
        out3[0]=ra; out3[1]=rb; out3[2]=rc; *outf=rf;
    }
}

__global__ __launch_bounds__(PTHR)
void fused_kernel(const float* __restrict__ pred_reg,
                  const float* __restrict__ pred_obj,
                  const float* __restrict__ pred_cls,
                  const float* __restrict__ gt_pts,
                  const int*   __restrict__ gt_lbl,
                  const int*   __restrict__ stride_p,
                  unsigned long long* __restrict__ cellkey,
                  float4* __restrict__ pA,
                  long long* __restrict__ pB,
                  float* __restrict__ out)
{
    cg::grid_group grid = cg::this_grid();
    const int pair = blockIdx.x;          // b*NG + g
    const int b    = pair >> 6;
    const int g    = pair & (NG - 1);
    const int tid  = threadIdx.x;
    const int lane = tid & 63;
    const int wid  = tid >> 6;
    const float s  = (float)(*stride_p);

    __shared__ unsigned long long keys[CAP];   // (dist_bits<<16)|n — unique 48-bit keys
    __shared__ int       hist[PTHR];
    __shared__ float     s3[NWAVE*3];
    __shared__ long long s1[NWAVE];
    __shared__ int       wsum[NWAVE];
    __shared__ int       scnt, sd, sp;

    /* ---- phase 0: init cellkey (grid-strided; gated by grid.sync below) ---- */
    for (int i = pair * PTHR + tid; i < BATCH * NCELL; i += NBLK * PTHR)
        cellkey[i] = INF64;

    /* pair-independent obj base: this block's slice of sum(-logsig(-x)) */
    float c_obj = 0.0f;
    if (tid < OBJ4_PER_BLK) {
        const float4 v = ((const float4*)pred_obj)[pair * OBJ4_PER_BLK + tid];
        c_obj = -log_sigmoid(-v.x) - log_sigmoid(-v.y)
                - log_sigmoid(-v.z) - log_sigmoid(-v.w);
    }

    /* cellkey init complete device-wide before any atomicMin claim */
    grid.sync();

    /* ---- per-pair geometry ---- */
    const float* gp = gt_pts + (size_t)pair * 6;
    const float Ax = gp[0], Ay = gp[1];
    const float Bx = gp[2], By = gp[3];
    const float Cx = gp[4], Cy = gp[5];

    const float vABx = Bx - Ax, vABy = By - Ay;
    const float vBCx = Cx - Bx, vBCy = Cy - By;
    const float vCAx = Ax - Cx, vCAy = Ay - Cy;
    const float invAB = 1.0f / (vABx * vABx + vABy * vABy + 1e-9f);
    const float invBC = 1.0f / (vBCx * vBCx + vBCy * vBCy + 1e-9f);
    const float invCA = 1.0f / (vCAx * vCAx + vCAy * vCAy + 1e-9f);

    const float xmin = fminf(Ax, fminf(Bx, Cx)) - ETA;
    const float xmax = fmaxf(Ax, fmaxf(Bx, Cx)) + ETA;
    const float ymin = fminf(Ay, fminf(By, Cy)) - ETA;
    const float ymax = fmaxf(Ay, fmaxf(By, Cy)) + ETA;
    const float inv_sf = 1.0f / s;
    int j0 = max(0,      (int)floorf(xmin * inv_sf - 0.5f) - 1);
    int j1 = min(WW - 1, (int)ceilf (xmax * inv_sf - 0.5f) + 1);
    int i0 = max(0,      (int)floorf(ymin * inv_sf - 0.5f) - 1);
    int i1 = min(HH - 1, (int)ceilf (ymax * inv_sf - 0.5f) + 1);
    const int nbw = j1 - j0 + 1;
    const int nbh = i1 - i0 + 1;
    const int nb  = (nbw > 0 && nbh > 0) ? nbw * nbh : 0;

    if (tid == 0) scnt = 0;
    __syncthreads();

    /* ---- bbox scan: collect positive cells ---- */
    for (int t = tid; t < nb; t += PTHR) {
        const int li = t / nbw;
        const int lj = t - li * nbw;
        const int i = i0 + li;
        const int j = j0 + lj;
        const float px = ((float)j + 0.5f) * s;
        const float py = ((float)i + 0.5f) * s;

        const float d1 = (px - Bx) * (Ay - By) - (Ax - Bx) * (py - By);
        const float d2 = (px - Cx) * (By - Cy) - (Bx - Cx) * (py - Cy);
        const float d3 = (px - Ax) * (Cy - Ay) - (Cx - Ax) * (py - Ay);
        const bool has_neg = (d1 < 0.0f) | (d2 < 0.0f) | (d3 < 0.0f);
        const bool has_pos = (d1 > 0.0f) | (d2 > 0.0f) | (d3 > 0.0f);
        const bool inside = !(has_neg && has_pos);

        float dsq = segsq(px - Ax, py - Ay, vABx, vABy, invAB);
        dsq = fminf(dsq, segsq(px - Bx, py - By, vBCx, vBCy, invBC));
        dsq = fminf(dsq, segsq(px - Cx, py - Cy, vCAx, vCAy, invCA));
        const float dist = sqrtf(dsq + 1e-12f);

        if (inside || dist <= ETA) {
            int slot = atomicAdd(&scnt, 1);
            if (slot < CAP) {
                const int n = i * WW + j;
                keys[slot] = (((unsigned long long)__float_as_uint(dist)) << 16) | (unsigned)n;
            }
        }
    }
    __syncthreads();

    const int M = min(scnt, CAP);
    unsigned long long T = INF64;

    if (M > KCAP) {
        /* exact 48-bit radix select of the KCAP-th smallest key */
        unsigned long long prefix = 0;
        int need = KCAP;
        for (int shift = 40; shift >= 0; shift -= 8) {
            hist[tid] = 0;
            __syncthreads();
            for (int t = tid; t < M; t += PTHR) {
                const unsigned long long k = keys[t];
                if ((k >> (shift + 8)) == prefix)
                    atomicAdd(&hist[(int)((k >> shift) & 0xFF)], 1);
            }
            __syncthreads();
            const int h = hist[tid];
            int incl = h;
            #pragma unroll
            for (int off = 1; off < 64; off <<= 1) {
                const int o = __shfl_up(incl, off);
                if (lane >= off) incl += o;
            }
            if (lane == 63) wsum[wid] = incl;
            __syncthreads();
            #pragma unroll
            for (int w = 0; w < NWAVE; ++w) if (w < wid) incl += wsum[w];
            const int excl = incl - h;
            if (excl < need && incl >= need) { sd = tid; sp = excl; }
            __syncthreads();
            prefix = (prefix << 8) | (unsigned)sd;
            need  -= sp;
            __syncthreads();
        }
        T = prefix;   // exactly KCAP keys <= T
    }

    /* ---- claims with telescoping compensation (replaces finish pass) ----
       On a winning atomicMin: add -fix(picked(me)); if a previous winner was
       displaced, add back +fix(picked(old)). llrintf is odd-symmetric, so each
       cell's chain telescopes exactly to -fix(picked(final_winner)),
       independent of interleaving. Integer accumulation -> deterministic. */
    const int tgt_mine = gt_lbl[pair];              // b*NG + g == pair
    const size_t bc = (size_t)b * NCLS * NCELL;

    float c_reg = 0.0f, c_lse = 0.0f;
    long long fix = 0;
    for (int t = tid; t < M; t += PTHR) {
        const unsigned long long k = keys[t];
        if (k > T) continue;
        const int   n    = (int)(k & 0xFFFFull);
        const float dist = __uint_as_float((unsigned)(k >> 16));
        const int   idx  = b * NCELL + n;

        const unsigned long long ck =
            (((unsigned long long)__float_as_uint(dist)) << 32) | (unsigned)g;
        const unsigned long long old = atomicMin(&cellkey[idx], ck);
        if (old > ck) {   // currently the best claim for this cell
            const float* pc = pred_cls + bc + n;
            if (old == INF64) {
                /* first claimer: obj pos term + lse (claim-order independent) */
                const float x = pred_obj[idx];
                c_obj += (-POS_W * log_sigmoid(x)) + log_sigmoid(-x);
                const float l0 = pc[0];
                const float l1 = pc[NCELL];
                const float l2 = pc[2 * NCELL];
                const float l3 = pc[3 * NCELL];
                const float m = fmaxf(fmaxf(l0, l1), fmaxf(l2, l3));
                c_lse += m + __logf(__expf(l0 - m) + __expf(l1 - m)
                                  + __expf(l2 - m) + __expf(l3 - m));
                const float pm = (tgt_mine == 0) ? l0 :
                                 (tgt_mine == 1) ? l1 :
                                 (tgt_mine == 2) ? l2 : l3;
                fix -= __float2ll_rn(pm * FIXS);
            } else {
                /* displaced a previous winner: compensate its picked term */
                const int gold = (int)(old & 0xFFFFFFFFull);
                const int tgto = gt_lbl[b * NG + gold];
                fix -= __float2ll_rn(pc[(size_t)tgt_mine * NCELL] * FIXS);
                fix += __float2ll_rn(pc[(size_t)tgto     * NCELL] * FIXS);
            }
        }

        const int i = n / WW;
        const int j = n - i * WW;
        const float ax = ((float)j + 0.5f) * s;
        const float ay = ((float)i + 0.5f) * s;

        const float g0x = (Ax - ax) * inv_sf, g0y = (Ay - ay) * inv_sf;
        const float g1x = (Bx - ax) * inv_sf, g1y = (By - ay) * inv_sf;
        const float g2x = (Cx - ax) * inv_sf, g2y = (Cy - ay) * inv_sf;

        const float* pr = pred_reg + (size_t)b * 6 * NCELL + n;
        const float p0x = pr[0 * NCELL], p0y = pr[1 * NCELL];
        const float p1x = pr[2 * NCELL], p1y = pr[3 * NCELL];
        const float p2x = pr[4 * NCELL], p2y = pr[5 * NCELL];

        c_reg += (p0x - g0x) * (p0x - g0x) + (p0y - g0y) * (p0y - g0y);

        const float d11 = sqrtf((p1x - g1x) * (p1x - g1x) + (p1y - g1y) * (p1y - g1y) + 1e-12f);
        const float d12 = sqrtf((p1x - g2x) * (p1x - g2x) + (p1y - g2y) * (p1y - g2y) + 1e-12f);
        const float d21 = sqrtf((p2x - g1x) * (p2x - g1x) + (p2y - g1y) * (p2y - g1y) + 1e-12f);
        const float d22 = sqrtf((p2x - g2x) * (p2x - g2x) + (p2y - g2y) * (p2y - g2y) + 1e-12f);

        c_reg += fminf(d11, d12) + fminf(d21, d22)
               + fminf(d11, d21) + fminf(d12, d22);
    }

    /* per-pair partials */
    float out3[3]; long long ftot;
    block_red(c_reg, c_obj, c_lse, fix, s3, s1, out3, &ftot);
    if (tid == 0) {
        pA[pair] = make_float4(out3[0], out3[1], out3[2], 0.0f);
        pB[pair] = ftot;
    }

    grid.sync();   // all partials + cellkey final and visible

    /* ---- final deterministic reduce by block 0 (NBLK == PTHR == 256) ---- */
    if (pair == 0) {
        const float4    v = pA[tid];
        const long long f = pB[tid];
        block_red(v.x, v.y, v.z, f, s3, s1, out3, &ftot);
        if (tid == 0) {
            out[0] = out3[0];
            out[1] = out3[1];
            out[2] = out3[2] + (float)((double)ftot * INV_FIXS);
        }
    }
}

extern "C" void kernel_launch(void* const* d_in, const int* in_sizes, int n_in,
                              void* d_out, int out_size, void* d_ws, size_t ws_size,
                              hipStream_t stream) {
    const float* pred_reg = (const float*)d_in[0];
    const float* pred_obj = (const float*)d_in[1];
    const float* pred_cls = (const float*)d_in[2];
    const float* gt_pts   = (const float*)d_in[3];
    const int*   gt_lbl   = (const int*)d_in[4];
    const int*   stride_p = (const int*)d_in[5];
    float* out = (float*)d_out;

    char* ws = (char*)d_ws;
    unsigned long long* cellkey = (unsigned long long*)ws;
    float4*    pA = (float4*)(ws + WS_PA_OFF);
    long long* pB = (long long*)(ws + WS_PB_OFF);

    (void)in_sizes; (void)n_in; (void)ws_size; (void)out_size;

    void* args[] = { &pred_reg, &pred_obj, &pred_cls, &gt_pts, &gt_lbl, &stride_p,
                     &cellkey, &pA, &pB, &out };
    hipLaunchCooperativeKernel(reinterpret_cast<void*>(fused_kernel),
                               dim3(NBLK), dim3(PTHR), args, 0, stream);
}

// Round 2
// 22.249 us; speedup vs baseline: 3.0680x; 3.0680x over previous
//
#include <hip/hip_runtime.h>
#include <stdint.h>

#define ETA    3.0f
#define KCAP   96
#define POS_W  1.2f
#define NG     64
#define BATCH  4
#define HH     192
#define WW     192
#define NCELL  (HH*WW)
#define NCLS   4
#define CAP    4096
#define PTHR   256
#define NWAVE  4
#define NBLK   (BATCH*NG)          /* 256 pair blocks */
#define SEGS   16                  /* cell segments per batch in resolve */
#define NB2    (BATCH*SEGS)        /* 64 resolve blocks */
#define SEGC   (NCELL/SEGS)        /* 2304 cells per segment */
#define BCLAIM (NG*KCAP)           /* 6144 claim slots per batch */
#define INF64  0xFFFFFFFFFFFFFFFFull
#define TOPBIT 0x8000000000000000ull

/* ws layout (NO host-side init; arrival init'd by pair_kernel block 0):
   [0]             arrival int
   [WS_CCNT_OFF]   ccnt   int[NBLK]             per-pair claim counts
   [WS_CLAIM_OFF]  claims u64[NBLK*KCAP]        (dist_bits<<32)|n
   [WS_PA_OFF]     pA float4[NBLK]              (reg, obj_base) partials
   [WS_PC_OFF]     pC float4[NB2]               (obj_corr, lse, picked)   */
#define WS_CCNT_OFF   16
#define WS_CLAIM_OFF  (WS_CCNT_OFF + NBLK*4)          /* 1040 */
#define WS_PA_OFF     (WS_CLAIM_OFF + NBLK*KCAP*8)    /* 197648 */
#define WS_PC_OFF     (WS_PA_OFF + NBLK*16)

#define OBJ4_PER_BLK 144   /* (B*NCELL floats / 4) / NBLK */

__device__ __forceinline__ float log_sigmoid(float x) {
    return fminf(x, 0.0f) - __logf(1.0f + __expf(-fabsf(x)));
}

__device__ __forceinline__ float segsq(float wx, float wy, float vx, float vy, float inv) {
    float t = (wx * vx + wy * vy) * inv;
    t = fminf(fmaxf(t, 0.0f), 1.0f);
    float dx = wx - t * vx;
    float dy = wy - t * vy;
    return dx * dx + dy * dy;
}

/* 5-float deterministic block reduction; result valid on tid 0 (in place) */
__device__ __forceinline__ void block_red5(float v[5], float* sbuf) {
    #pragma unroll
    for (int off = 32; off > 0; off >>= 1) {
        #pragma unroll
        for (int q = 0; q < 5; ++q) v[q] += __shfl_down(v[q], off);
    }
    const int lane = threadIdx.x & 63;
    const int wid  = threadIdx.x >> 6;
    __syncthreads();
    if (lane == 0) {
        #pragma unroll
        for (int q = 0; q < 5; ++q) sbuf[wid * 5 + q] = v[q];
    }
    __syncthreads();
    if (threadIdx.x == 0) {
        #pragma unroll
        for (int q = 0; q < 5; ++q) {
            float r = 0.0f;
            #pragma unroll
            for (int w = 0; w < NWAVE; ++w) r += sbuf[w * 5 + q];
            v[q] = r;
        }
    }
}

__global__ __launch_bounds__(PTHR)
void pair_kernel(const float* __restrict__ pred_reg,
                 const float* __restrict__ pred_obj,
                 const float* __restrict__ gt_pts,
                 const int*   __restrict__ stride_p,
                 int* __restrict__ ccnt,
                 unsigned long long* __restrict__ claims,
                 float4* __restrict__ pA,
                 int* __restrict__ arrival)
{
    const int pair = blockIdx.x;          // b*NG + g
    const int b    = pair >> 6;
    const int tid  = threadIdx.x;
    const int lane = tid & 63;
    const int wid  = tid >> 6;
    const float s  = (float)(*stride_p);

    __shared__ unsigned long long keys[CAP];   // (dist_bits<<16)|n — unique 48-bit keys
    __shared__ int   hist[PTHR];
    __shared__ float sbuf[NWAVE * 5];
    __shared__ int   wsum[NWAVE];
    __shared__ int   scnt, ccl, sd, sp;

    /* arrival counter for resolve_kernel (visible after this dispatch ends) */
    if (pair == 0 && tid == 0) *arrival = 0;

    /* pair-independent obj base: this block's slice of sum(-logsig(-x)) */
    float c_obj = 0.0f;
    if (tid < OBJ4_PER_BLK) {
        const float4 v = ((const float4*)pred_obj)[pair * OBJ4_PER_BLK + tid];
        c_obj = -log_sigmoid(-v.x) - log_sigmoid(-v.y)
                - log_sigmoid(-v.z) - log_sigmoid(-v.w);
    }

    const float* gp = gt_pts + (size_t)pair * 6;
    const float Ax = gp[0], Ay = gp[1];
    const float Bx = gp[2], By = gp[3];
    const float Cx = gp[4], Cy = gp[5];

    const float vABx = Bx - Ax, vABy = By - Ay;
    const float vBCx = Cx - Bx, vBCy = Cy - By;
    const float vCAx = Ax - Cx, vCAy = Ay - Cy;
    const float invAB = 1.0f / (vABx * vABx + vABy * vABy + 1e-9f);
    const float invBC = 1.0f / (vBCx * vBCx + vBCy * vBCy + 1e-9f);
    const float invCA = 1.0f / (vCAx * vCAx + vCAy * vCAy + 1e-9f);

    const float xmin = fminf(Ax, fminf(Bx, Cx)) - ETA;
    const float xmax = fmaxf(Ax, fmaxf(Bx, Cx)) + ETA;
    const float ymin = fminf(Ay, fminf(By, Cy)) - ETA;
    const float ymax = fmaxf(Ay, fmaxf(By, Cy)) + ETA;
    const float inv_sf = 1.0f / s;
    int j0 = max(0,      (int)floorf(xmin * inv_sf - 0.5f) - 1);
    int j1 = min(WW - 1, (int)ceilf (xmax * inv_sf - 0.5f) + 1);
    int i0 = max(0,      (int)floorf(ymin * inv_sf - 0.5f) - 1);
    int i1 = min(HH - 1, (int)ceilf (ymax * inv_sf - 0.5f) + 1);
    const int nbw = j1 - j0 + 1;
    const int nbh = i1 - i0 + 1;
    const int nb  = (nbw > 0 && nbh > 0) ? nbw * nbh : 0;

    if (tid == 0) { scnt = 0; ccl = 0; }
    __syncthreads();

    /* ---- bbox scan: collect positive cells ---- */
    for (int t = tid; t < nb; t += PTHR) {
        const int li = t / nbw;
        const int lj = t - li * nbw;
        const int i = i0 + li;
        const int j = j0 + lj;
        const float px = ((float)j + 0.5f) * s;
        const float py = ((float)i + 0.5f) * s;

        const float d1 = (px - Bx) * (Ay - By) - (Ax - Bx) * (py - By);
        const float d2 = (px - Cx) * (By - Cy) - (Bx - Cx) * (py - Cy);
        const float d3 = (px - Ax) * (Cy - Ay) - (Cx - Ax) * (py - Ay);
        const bool has_neg = (d1 < 0.0f) | (d2 < 0.0f) | (d3 < 0.0f);
        const bool has_pos = (d1 > 0.0f) | (d2 > 0.0f) | (d3 > 0.0f);
        const bool inside = !(has_neg && has_pos);

        float dsq = segsq(px - Ax, py - Ay, vABx, vABy, invAB);
        dsq = fminf(dsq, segsq(px - Bx, py - By, vBCx, vBCy, invBC));
        dsq = fminf(dsq, segsq(px - Cx, py - Cy, vCAx, vCAy, invCA));
        const float dist = sqrtf(dsq + 1e-12f);

        if (inside || dist <= ETA) {
            int slot = atomicAdd(&scnt, 1);
            if (slot < CAP) {
                const int n = i * WW + j;
                keys[slot] = (((unsigned long long)__float_as_uint(dist)) << 16) | (unsigned)n;
            }
        }
    }
    __syncthreads();

    const int M = min(scnt, CAP);
    unsigned long long T = INF64;

    if (M > KCAP) {
        /* exact 48-bit radix select of the KCAP-th smallest key */
        unsigned long long prefix = 0;
        int need = KCAP;
        for (int shift = 40; shift >= 0; shift -= 8) {
            hist[tid] = 0;
            __syncthreads();
            for (int t = tid; t < M; t += PTHR) {
                const unsigned long long k = keys[t];
                if ((k >> (shift + 8)) == prefix)
                    atomicAdd(&hist[(int)((k >> shift) & 0xFF)], 1);
            }
            __syncthreads();
            const int h = hist[tid];
            int incl = h;
            #pragma unroll
            for (int off = 1; off < 64; off <<= 1) {
                const int o = __shfl_up(incl, off);
                if (lane >= off) incl += o;
            }
            if (lane == 63) wsum[wid] = incl;
            __syncthreads();
            #pragma unroll
            for (int w = 0; w < NWAVE; ++w) if (w < wid) incl += wsum[w];
            const int excl = incl - h;
            if (excl < need && incl >= need) { sd = tid; sp = excl; }
            __syncthreads();
            prefix = (prefix << 8) | (unsigned)sd;
            need  -= sp;
            __syncthreads();
        }
        T = prefix;   // exactly KCAP keys <= T
    }

    /* ---- claim emit + reg loss (resolution deferred to resolve_kernel) ---- */
    float c_reg = 0.0f;
    for (int t = tid; t < M; t += PTHR) {
        const unsigned long long k = keys[t];
        if (k > T) continue;
        const int n = (int)(k & 0xFFFFull);

        const int slot = atomicAdd(&ccl, 1);
        if (slot < KCAP)
            claims[(size_t)pair * KCAP + slot] =
                ((k >> 16) << 32) | (unsigned long long)(unsigned)n;

        const int i = n / WW;
        const int j = n - i * WW;
        const float ax = ((float)j + 0.5f) * s;
        const float ay = ((float)i + 0.5f) * s;

        const float g0x = (Ax - ax) * inv_sf, g0y = (Ay - ay) * inv_sf;
        const float g1x = (Bx - ax) * inv_sf, g1y = (By - ay) * inv_sf;
        const float g2x = (Cx - ax) * inv_sf, g2y = (Cy - ay) * inv_sf;

        const float* pr = pred_reg + (size_t)b * 6 * NCELL + n;
        const float p0x = pr[0 * NCELL], p0y = pr[1 * NCELL];
        const float p1x = pr[2 * NCELL], p1y = pr[3 * NCELL];
        const float p2x = pr[4 * NCELL], p2y = pr[5 * NCELL];

        c_reg += (p0x - g0x) * (p0x - g0x) + (p0y - g0y) * (p0y - g0y);

        const float d11 = sqrtf((p1x - g1x) * (p1x - g1x) + (p1y - g1y) * (p1y - g1y) + 1e-12f);
        const float d12 = sqrtf((p1x - g2x) * (p1x - g2x) + (p1y - g2y) * (p1y - g2y) + 1e-12f);
        const float d21 = sqrtf((p2x - g1x) * (p2x - g1x) + (p2y - g1y) * (p2y - g1y) + 1e-12f);
        const float d22 = sqrtf((p2x - g2x) * (p2x - g2x) + (p2y - g2y) * (p2y - g2y) + 1e-12f);

        c_reg += fminf(d11, d12) + fminf(d21, d22)
               + fminf(d11, d21) + fminf(d12, d22);
    }
    __syncthreads();   // ccl final
    if (tid == 0) ccnt[pair] = min(ccl, KCAP);

    float v[5] = { c_reg, c_obj, 0.0f, 0.0f, 0.0f };
    block_red5(v, sbuf);
    if (tid == 0) pA[pair] = make_float4(v[0], v[1], 0.0f, 0.0f);
}

__global__ __launch_bounds__(PTHR)
void resolve_kernel(const float* __restrict__ pred_obj,
                    const float* __restrict__ pred_cls,
                    const int*   __restrict__ gt_lbl,
                    const int*   __restrict__ ccnt,
                    const unsigned long long* __restrict__ claims,
                    const float4* __restrict__ pA,
                    float4* __restrict__ pC,
                    int* __restrict__ arrival,
                    float* __restrict__ out)
{
    const int blk = blockIdx.x;
    const int b   = blk >> 4;               /* blk / SEGS */
    const int seg = blk & (SEGS - 1);
    const int n0  = seg * SEGC;
    const int tid = threadIdx.x;

    __shared__ unsigned int       table[SEGC];     /* 9 KB: per-cell (dist|g) min */
    __shared__ unsigned long long cl[BCLAIM];      /* 48 KB: compacted in-seg claims */
    __shared__ int   cnts[NG];
    __shared__ float sbuf[NWAVE * 5];
    __shared__ int   ccl, islast;

    if (tid < NG) cnts[tid] = ccnt[b * NG + tid];
    if (tid == 0) { ccl = 0; islast = 0; }
    for (int i = tid; i < SEGC; i += PTHR) table[i] = 0xFFFFFFFFu;
    __syncthreads();

    /* pass 1: compact my-segment claims into LDS + exact dist_bits atomicMin */
    const unsigned long long* bcl = claims + (size_t)b * BCLAIM;
    for (int sIdx = tid; sIdx < BCLAIM; sIdx += PTHR) {
        const int pg = sIdx / KCAP;
        const int r  = sIdx - pg * KCAP;
        if (r < cnts[pg]) {
            const unsigned long long e = bcl[sIdx];
            const int ln = (int)(e & 0xFFFFull) - n0;
            if ((unsigned)ln < (unsigned)SEGC) {
                const int i = atomicAdd(&ccl, 1);
                cl[i] = e | ((unsigned long long)pg << 16);   /* stash g in free bits */
                atomicMin(&table[ln], (unsigned)(e >> 32));
            }
        }
    }
    __syncthreads();
    const int NC = ccl;

    /* pass 2a: mark dist-winners while table still holds dists */
    for (int i = tid; i < NC; i += PTHR) {
        const unsigned long long e = cl[i];
        const int ln = (int)(e & 0xFFFFull) - n0;
        if (table[ln] == (unsigned)(e >> 32)) cl[i] = e | TOPBIT;
    }
    __syncthreads();
    /* pass 2b: tie-break by g (g<64 < any dist bits since dist>=1e-6) */
    for (int i = tid; i < NC; i += PTHR) {
        const unsigned long long e = cl[i];
        if (e & TOPBIT) {
            const int ln = (int)(e & 0xFFFFull) - n0;
            atomicMin(&table[ln], (unsigned)((e >> 16) & 63ull));
        }
    }
    __syncthreads();

    /* pass 3: unique winners compute obj-correction, lse, picked */
    float v[5] = { 0.0f, 0.0f, 0.0f, 0.0f, 0.0f };
    const size_t bc = (size_t)b * NCLS * NCELL;
    for (int i = tid; i < NC; i += PTHR) {
        const unsigned long long e = cl[i];
        if (!(e & TOPBIT)) continue;
        const int n = (int)(e & 0xFFFFull);
        const int g = (int)((e >> 16) & 63ull);
        if (table[n - n0] != (unsigned)g) continue;

        const float x = pred_obj[b * NCELL + n];
        v[0] += (-POS_W * log_sigmoid(x)) + log_sigmoid(-x);

        const float* pc = pred_cls + bc + n;
        const float l0 = pc[0];
        const float l1 = pc[NCELL];
        const float l2 = pc[2 * NCELL];
        const float l3 = pc[3 * NCELL];
        const float m = fmaxf(fmaxf(l0, l1), fmaxf(l2, l3));
        v[1] += m + __logf(__expf(l0 - m) + __expf(l1 - m)
                         + __expf(l2 - m) + __expf(l3 - m));
        const int tgt = gt_lbl[b * NG + g];
        v[2] += (tgt == 0) ? l0 : (tgt == 1) ? l1 : (tgt == 2) ? l2 : l3;
    }
    block_red5(v, sbuf);

    if (tid == 0) {
        pC[blk] = make_float4(v[0], v[1], v[2], 0.0f);
        __threadfence();
        const int old = atomicAdd(arrival, 1);
        if (old == NB2 - 1) islast = 1;
    }
    __syncthreads();
    if (!islast) return;
    __threadfence();

    /* last-arriving block: deterministic final reduce (NBLK == PTHR == 256) */
    const float4 a = pA[tid];
    const float4 c = (tid < NB2) ? pC[tid] : make_float4(0.f, 0.f, 0.f, 0.f);
    float w[5] = { a.x, a.y, c.x, c.y, c.z };
    block_red5(w, sbuf);
    if (tid == 0) {
        out[0] = w[0];               /* reg */
        out[1] = w[1] + w[2];        /* obj base + obj corrections */
        out[2] = w[3] - w[4];        /* lse - picked */
    }
}

extern "C" void kernel_launch(void* const* d_in, const int* in_sizes, int n_in,
                              void* d_out, int out_size, void* d_ws, size_t ws_size,
                              hipStream_t stream) {
    const float* pred_reg = (const float*)d_in[0];
    const float* pred_obj = (const float*)d_in[1];
    const float* pred_cls = (const float*)d_in[2];
    const float* gt_pts   = (const float*)d_in[3];
    const int*   gt_lbl   = (const int*)d_in[4];
    const int*   stride_p = (const int*)d_in[5];
    float* out = (float*)d_out;

    char* ws = (char*)d_ws;
    int* arrival = (int*)ws;
    int* ccnt    = (int*)(ws + WS_CCNT_OFF);
    unsigned long long* claims = (unsigned long long*)(ws + WS_CLAIM_OFF);
    float4* pA = (float4*)(ws + WS_PA_OFF);
    float4* pC = (float4*)(ws + WS_PC_OFF);

    (void)in_sizes; (void)n_in; (void)ws_size; (void)out_size;

    hipLaunchKernelGGL(pair_kernel, dim3(NBLK), dim3(PTHR), 0, stream,
                       pred_reg, pred_obj, gt_pts, stride_p,
                       ccnt, claims, pA, arrival);
    hipLaunchKernelGGL(resolve_kernel, dim3(NB2), dim3(PTHR), 0, stream,
                       pred_obj, pred_cls, gt_lbl, ccnt, claims, pA,
                       pC, arrival, out);
}